// Round 7
// baseline (108.225 us; speedup 1.0000x reference)
//
#include <hip/hip_runtime.h>
#include <math.h>

#define NU_ 12000
#define NI_ 16000
#define NPU 12288   // padded Et stride
#define NPI 16384   // padded Et stride
#define DD 64
#define BB 1024
#define KC 256      // K-chunk (floats) per block iteration
#define SPL 8

// packed-mask byte counts / offsets (elements/8)
#define MBU_ (BB * (NU_ / 8))          // 1,536,000
#define MBI_ (BB * (NI_ / 8))          // 2,048,000
#define MB_TOTAL (MBU_ + 2 * MBI_)     // 5,632,000

typedef unsigned short ushort_t;
typedef __bf16 bf16x8 __attribute__((ext_vector_type(8)));
typedef float  f32x4  __attribute__((ext_vector_type(4)));
typedef unsigned short ushort4v __attribute__((ext_vector_type(4)));

static __device__ __forceinline__ ushort_t f2bf(float f) {
    __bf16 h = (__bf16)f;
    return __builtin_bit_cast(unsigned short, h);
}

// ---------------------------------------------------------------------------
// Kernel P: pack masks to bits. Pure sequential stream at full HBM BW.
// Element e -> byte e/8, bit e%8  (bit set = keep).
// ---------------------------------------------------------------------------
__global__ __launch_bounds__(256) void gde_pack(
    const float* __restrict__ mu, const float* __restrict__ mp,
    const float* __restrict__ mn, unsigned char* __restrict__ Mb)
{
    const int j = blockIdx.y;
    const float* src; size_t nb, off;
    if (j == 0)      { src = mu; nb = MBU_; off = 0; }
    else if (j == 1) { src = mp; nb = MBI_; off = MBU_; }
    else             { src = mn; nb = MBI_; off = MBU_ + MBI_; }
    unsigned char* dst = Mb + off;
    const size_t stride = (size_t)gridDim.x * 256;
    for (size_t i = (size_t)blockIdx.x * 256 + threadIdx.x; i < nb; i += stride) {
        const float4 v0 = *(const float4*)(src + 8 * i);
        const float4 v1 = *(const float4*)(src + 8 * i + 4);
        unsigned int b = 0;
        b |= (v0.x >= 0.1f) ?   1u : 0u;
        b |= (v0.y >= 0.1f) ?   2u : 0u;
        b |= (v0.z >= 0.1f) ?   4u : 0u;
        b |= (v0.w >= 0.1f) ?   8u : 0u;
        b |= (v1.x >= 0.1f) ?  16u : 0u;
        b |= (v1.y >= 0.1f) ?  32u : 0u;
        b |= (v1.z >= 0.1f) ?  64u : 0u;
        b |= (v1.w >= 0.1f) ? 128u : 0u;
        dst[i] = (unsigned char)b;
    }
}

// ---------------------------------------------------------------------------
// Kernel 0: transpose + cast E[N][64] f32 -> Et[64][Np] bf16, zero-padded
// columns N..Np (GEMM tail/stale reads multiply by exactly 0).
// ---------------------------------------------------------------------------
__global__ __launch_bounds__(256) void gde_transpose(
    const float* __restrict__ E, ushort_t* __restrict__ Et, int N, int Np)
{
    __shared__ ushort_t Ls[64][65];
    const int n0  = blockIdx.x * 64;
    const int tid = threadIdx.x;
    const int dg  = tid & 15;
    const int nr  = tid >> 4;
#pragma unroll
    for (int nn = 0; nn < 4; ++nn) {
        const int nl = nn * 16 + nr;
        const int n  = n0 + nl;
        float4 v = make_float4(0.f, 0.f, 0.f, 0.f);
        if (n < N) v = *(const float4*)(E + (size_t)n * DD + dg * 4);
        Ls[nl][dg * 4 + 0] = f2bf(v.x);
        Ls[nl][dg * 4 + 1] = f2bf(v.y);
        Ls[nl][dg * 4 + 2] = f2bf(v.z);
        Ls[nl][dg * 4 + 3] = f2bf(v.w);
    }
    __syncthreads();
    const int d   = tid & 63;
    const int nl0 = (tid >> 6) * 16;
#pragma unroll
    for (int g = 0; g < 4; ++g) {
        ushort4v t;
#pragma unroll
        for (int i = 0; i < 4; ++i) t[i] = Ls[nl0 + g * 4 + i][d];
        *(ushort4v*)(Et + (size_t)d * Np + n0 + nl0 + g * 4) = t;
    }
}

// ---------------------------------------------------------------------------
// Kernel 1: gathered GEMM with bit-packed masks. Counted-vmcnt raw-barrier
// pipeline (round-6 structure): loads for chunk t+1 stay in flight through
// compute of chunk t. L-only staging (8 float4/lane) + 8 mask bytes.
// ---------------------------------------------------------------------------
__global__ __launch_bounds__(256, 3) void gde_gemm(
    const float* __restrict__ L_u, const float* __restrict__ L_i,
    const ushort_t* __restrict__ EtU, const ushort_t* __restrict__ EtI,
    const unsigned char* __restrict__ Mb,
    const int* __restrict__ user, const int* __restrict__ pos,
    const int* __restrict__ nega,
    float* __restrict__ P, int S)
{
    __shared__ ushort_t As[32 * 256];   // 16 KB, row stride 512B, XOR-swizzled

    const int rt  = blockIdx.x;   // 0..31
    const int s   = blockIdx.y;   // 0..S-1
    const int j   = blockIdx.z;   // 0=user,1=pos,2=nega
    const int tid = threadIdx.x;
    const int w   = tid >> 6;
    const int l   = tid & 63;

    const float* L; const ushort_t* Et; const unsigned char* MbB; const int* idx;
    int N, Np;
    if (j == 0)      { L = L_u; Et = EtU; MbB = Mb;               idx = user; N = NU_; Np = NPU; }
    else if (j == 1) { L = L_i; Et = EtI; MbB = Mb + MBU_;        idx = pos;  N = NI_; Np = NPI; }
    else             { L = L_i; Et = EtI; MbB = Mb + MBU_ + MBI_; idx = nega; N = NI_; Np = NPI; }

    const int base = rt * 32;
    unsigned int Loff[8], Boff[8];
#pragma unroll
    for (int r = 0; r < 8; ++r) {
        const int row = base + w * 8 + r;
        Loff[r] = (unsigned int)idx[row] * (unsigned int)(N * 4);   // byte off
        Boff[r] = (unsigned int)row * (unsigned int)(N / 8);        // byte off
    }

    const int dcol = l & 15;
    const int g4   = l >> 4;
    const ushort_t* Eb[4];
#pragma unroll
    for (int df = 0; df < 4; ++df) Eb[df] = Et + (size_t)(df * 16 + dcol) * Np;

    f32x4 acc[8];
#pragma unroll
    for (int i = 0; i < 8; ++i) acc[i] = (f32x4){0.f, 0.f, 0.f, 0.f};

    const int nc  = (N + KC - 1) / KC;        // 47 or 63
    const int kb0 = (s * nc) / S;
    const int kb1 = ((s + 1) * nc) / S;

    float4 La[8];
    unsigned int mbv[8];
#pragma unroll
    for (int r = 0; r < 8; ++r) { La[r] = make_float4(0.f,0.f,0.f,0.f); mbv[r] = 0; }

    // ---- prologue: issue chunk kb0's loads (per-lane OOB-guarded)
    {
        const int kg = kb0 * KC + 4 * l;
        if (kg < N) {
            const size_t boff = (size_t)kg * 4u;
            const unsigned int moff = (unsigned int)(kb0 * KC / 8 + (l >> 1));
#pragma unroll
            for (int r = 0; r < 8; ++r) {
                La[r]  = *(const float4*)((const char*)L + Loff[r] + boff);
                mbv[r] = MbB[Boff[r] + moff];
            }
        }
    }

    for (int kb = kb0; kb < kb1; ++kb) {
        // ---- STORE: select (bit) + convert current chunk regs -> swizzled LDS
        //      (compiler's vmcnt wait for La/mbv lands here — the data dep)
        const unsigned int sh = (l & 1) << 2;
#pragma unroll
        for (int r = 0; r < 8; ++r) {
            const int row = w * 8 + r;
            const unsigned int bits = mbv[r] >> sh;
            ushort4v t;
            t[0] = (bits & 1u) ? f2bf(La[r].x) : (ushort_t)0;
            t[1] = (bits & 2u) ? f2bf(La[r].y) : (ushort_t)0;
            t[2] = (bits & 4u) ? f2bf(La[r].z) : (ushort_t)0;
            t[3] = (bits & 8u) ? f2bf(La[r].w) : (ushort_t)0;
            *(ushort4v*)((char*)As + (row << 9) + ((l * 8) ^ ((row & 7) << 4))) = t;
        }

        // ---- Et B-frag preload for THIS chunk (L2-resident) -> regs.
        //      Issued BEFORE next-chunk staging so compute's wait is counted.
        bf16x8 bfr[2][4];
#pragma unroll
        for (int h = 0; h < 2; ++h) {
            const int kk = kb * KC + (2 * w + h) * 32 + 8 * g4;
#pragma unroll
            for (int df = 0; df < 4; ++df)
                bfr[h][df] = *(const bf16x8*)(Eb[df] + kk);
        }
        asm volatile("" ::: "memory");   // pin Et-issue before staging-issue

        // ---- ISSUE next chunk's loads (stay in flight across the barrier)
        if (kb + 1 < kb1) {
            const int kg = (kb + 1) * KC + 4 * l;
            if (kg < N) {
                const size_t boff = (size_t)kg * 4u;
                const unsigned int moff = (unsigned int)((kb + 1) * KC / 8 + (l >> 1));
#pragma unroll
                for (int r = 0; r < 8; ++r) {
                    La[r]  = *(const float4*)((const char*)L + Loff[r] + boff);
                    mbv[r] = MbB[Boff[r] + moff];
                }
            }
            // stale lanes keep finite regs; Et zero-pad nullifies their product
        }

        // ---- barrier WITHOUT vmcnt drain (raw s_barrier, lgkm only)
        asm volatile("s_waitcnt lgkmcnt(0)" ::: "memory");
        __builtin_amdgcn_s_barrier();
        asm volatile("" ::: "memory");

        // ---- COMPUTE: wave w covers k-steps 2w, 2w+1 of this chunk
#pragma unroll
        for (int h = 0; h < 2; ++h) {
            const int ks = 2 * w + h;
            const int cb = 64 * ks + 16 * g4;          // byte offset in LDS row
            const int r0 = dcol, r1 = 16 + dcol;
            const bf16x8 af0 = *(const bf16x8*)((char*)As + (r0 << 9) + (cb ^ ((r0 & 7) << 4)));
            const bf16x8 af1 = *(const bf16x8*)((char*)As + (r1 << 9) + (cb ^ ((r1 & 7) << 4)));
            acc[0] = __builtin_amdgcn_mfma_f32_16x16x32_bf16(af0, bfr[h][0], acc[0], 0, 0, 0);
            acc[1] = __builtin_amdgcn_mfma_f32_16x16x32_bf16(af0, bfr[h][1], acc[1], 0, 0, 0);
            acc[2] = __builtin_amdgcn_mfma_f32_16x16x32_bf16(af0, bfr[h][2], acc[2], 0, 0, 0);
            acc[3] = __builtin_amdgcn_mfma_f32_16x16x32_bf16(af0, bfr[h][3], acc[3], 0, 0, 0);
            acc[4] = __builtin_amdgcn_mfma_f32_16x16x32_bf16(af1, bfr[h][0], acc[4], 0, 0, 0);
            acc[5] = __builtin_amdgcn_mfma_f32_16x16x32_bf16(af1, bfr[h][1], acc[5], 0, 0, 0);
            acc[6] = __builtin_amdgcn_mfma_f32_16x16x32_bf16(af1, bfr[h][2], acc[6], 0, 0, 0);
            acc[7] = __builtin_amdgcn_mfma_f32_16x16x32_bf16(af1, bfr[h][3], acc[7], 0, 0, 0);
        }

        // ---- protect LDS from next iter's STORE
        asm volatile("" ::: "memory");
        __builtin_amdgcn_s_barrier();
        asm volatile("" ::: "memory");
    }

    // ---- write partial: slice seff = s*4 + w
    float* Pb = P + ((size_t)(j * (S * 4) + s * 4 + w) * BB + base) * DD;
#pragma unroll
    for (int ri = 0; ri < 4; ++ri) {
        const int m = g4 * 4 + ri;
        Pb[(size_t)m * DD +  0 + dcol] = acc[0][ri];
        Pb[(size_t)m * DD + 16 + dcol] = acc[1][ri];
        Pb[(size_t)m * DD + 32 + dcol] = acc[2][ri];
        Pb[(size_t)m * DD + 48 + dcol] = acc[3][ri];
        Pb[(size_t)(m + 16) * DD +  0 + dcol] = acc[4][ri];
        Pb[(size_t)(m + 16) * DD + 16 + dcol] = acc[5][ri];
        Pb[(size_t)(m + 16) * DD + 32 + dcol] = acc[6][ri];
        Pb[(size_t)(m + 16) * DD + 48 + dcol] = acc[7][ri];
    }
}

// ---------------------------------------------------------------------------
// Kernel 2: per-batch-row finalize (4 rows per 256-thread block).
// ---------------------------------------------------------------------------
__global__ __launch_bounds__(256) void gde_finalize(
    const float* __restrict__ P, int Seff,
    float* __restrict__ term, float* __restrict__ regp)
{
    const int b    = blockIdx.x * 4 + (threadIdx.x >> 6);
    const int lane = threadIdx.x & 63;
    const size_t joff = (size_t)Seff * BB * DD;

    float fu = 0.f, fp_ = 0.f, fn = 0.f;
    for (int s = 0; s < Seff; ++s) {
        const size_t base = ((size_t)s * BB + b) * DD + lane;
        fu  += P[base];
        fp_ += P[base + joff];
        fn  += P[base + 2 * joff];
    }

    float rp = fu * fp_;
    float rn = fu * fn;
    float rg = fu * fu + fp_ * fp_ + fn * fn;
#pragma unroll
    for (int o = 32; o > 0; o >>= 1) {
        rp += __shfl_xor(rp, o);
        rn += __shfl_xor(rn, o);
        rg += __shfl_xor(rg, o);
    }

    if (lane == 0) {
        const float sn = 1.0f / (1.0f + expf(-rn));
        const float w  = 1.0f - log10f(1.0f - fminf(sn, 0.99f));
        const float x  = rp - w * rn;
        const float t  = -x;   // -log(sigmoid(x)) = softplus(-x), finite
        term[b] = fmaxf(t, 0.0f) + log1pf(expf(-fabsf(t)));
        regp[b] = rg;
    }
}

// ---------------------------------------------------------------------------
// Kernel 3: deterministic scalar reduction.
// ---------------------------------------------------------------------------
__global__ __launch_bounds__(256) void gde_reduce(
    const float* __restrict__ term, const float* __restrict__ regp,
    float* __restrict__ out)
{
    __shared__ float sm[256];
    const int t = threadIdx.x;
    float v = 0.f;
    for (int i = t; i < BB; i += 256)
        v += term[i] + 0.01f * regp[i];
    sm[t] = v;
    __syncthreads();
    for (int o = 128; o > 0; o >>= 1) {
        if (t < o) sm[t] += sm[t + o];
        __syncthreads();
    }
    if (t == 0) out[0] = sm[0] / (float)BB;
}

extern "C" void kernel_launch(void* const* d_in, const int* in_sizes, int n_in,
                              void* d_out, int out_size, void* d_ws, size_t ws_size,
                              hipStream_t stream)
{
    const float* L_u = (const float*)d_in[0];
    const float* L_i = (const float*)d_in[1];
    const float* ue  = (const float*)d_in[2];
    const float* ie  = (const float*)d_in[3];
    const float* mu  = (const float*)d_in[4];
    const float* mp  = (const float*)d_in[5];
    const float* mn  = (const float*)d_in[6];
    const int* user  = (const int*)d_in[7];
    const int* pos   = (const int*)d_in[8];
    const int* nega  = (const int*)d_in[9];
    float* out = (float*)d_out;

    const size_t etU_b  = (size_t)DD * NPU * 2;
    const size_t etI_b  = (size_t)DD * NPI * 2;
    const size_t slice  = (size_t)3 * BB * DD * 4;    // per-seff P bytes
    const size_t fixed  = etU_b + etI_b + MB_TOTAL + 2 * BB * 4 + 512;
    int S = SPL;
    while (S > 1 && (size_t)(4 * S) * slice + fixed > ws_size) --S;
    const int Seff = 4 * S;

    float*         P    = (float*)d_ws;
    ushort_t*      EtU  = (ushort_t*)((char*)d_ws + (size_t)Seff * slice);
    ushort_t*      EtI  = (ushort_t*)((char*)EtU + etU_b);
    unsigned char* Mb   = (unsigned char*)((char*)EtI + etI_b);
    float*         term = (float*)((char*)Mb + ((MB_TOTAL + 255) & ~255ull));
    float*         regp = term + BB;

    gde_pack<<<dim3(2048, 3), dim3(256), 0, stream>>>(mu, mp, mn, Mb);
    gde_transpose<<<dim3(NPU / 64), dim3(256), 0, stream>>>(ue, EtU, NU_, NPU);
    gde_transpose<<<dim3(NPI / 64), dim3(256), 0, stream>>>(ie, EtI, NI_, NPI);

    gde_gemm<<<dim3(32, S, 3), dim3(256), 0, stream>>>(
        L_u, L_i, EtU, EtI, Mb, user, pos, nega, P, S);

    gde_finalize<<<dim3(BB / 4), dim3(256), 0, stream>>>(P, Seff, term, regp);
    gde_reduce<<<dim3(1), dim3(256), 0, stream>>>(term, regp, out);
}